// Round 13
// baseline (292.457 us; speedup 1.0000x reference)
//
#include <hip/hip_runtime.h>
#include <math.h>

#define NPTS 9216          // 96*96
#define CDIM 256
#define WW 96
#define W2 192
#define MACT (192*192)
#define RB 72              // 9216/128 row/col blocks

typedef __attribute__((ext_vector_type(8))) short short8;
typedef __attribute__((ext_vector_type(4))) float f32x4;

// branch-free (max, second, argmax-of-max) tuple ops; ties -> keep current (output-invariant)
__device__ __forceinline__ void tmerge(float& m, float& s, int& i, float om, float os, int oi) {
    float lo = fminf(m, om);
    i = (om > m) ? oi : i;
    m = fmaxf(m, om);
    s = fmaxf(fmaxf(s, os), lo);
}

__device__ __forceinline__ void feed(float v, int i, float& v0, int& i0, float& v1, int& i1) {
    if (v > v0) { v1 = v0; i1 = i0; v0 = v; i0 = i; }
    else if (v > v1) { v1 = v; i1 = i; }
}

__device__ __forceinline__ unsigned short f2bf(float f) {
    unsigned u = __float_as_uint(f);
    unsigned r = (u + 0x7fffu + ((u >> 16) & 1u)) >> 16;
    return (unsigned short)r;
}
__device__ __forceinline__ float bf2f(unsigned short h) {
    return __uint_as_float(((unsigned)h) << 16);
}

__device__ __forceinline__ void gload16(const unsigned short* g, unsigned short* l) {
    __builtin_amdgcn_global_load_lds((const __attribute__((address_space(1))) unsigned int*)g,
                                     (__attribute__((address_space(3))) unsigned int*)l, 16, 0, 0);
}

__global__ void norm_inv_k(const float* __restrict__ src, float* __restrict__ inv) {
    int p = blockIdx.x * blockDim.x + threadIdx.x;
    if (p >= NPTS) return;
    float s = 0.f;
    for (int c = 0; c < CDIM; ++c) { float v = src[(size_t)c * NPTS + p]; s += v * v; }
    inv[p] = 1.0f / sqrtf(s);
}

__global__ __launch_bounds__(256) void prep_split_k(const float* __restrict__ src, const float* __restrict__ inv,
                                                    unsigned short* __restrict__ hiT, unsigned short* __restrict__ loT) {
    __shared__ float tile[64][65];
    int p0 = blockIdx.x * 64;
    int c0 = blockIdx.y * 64;
    int t = threadIdx.x;
    int cl = t >> 4, pl4 = (t & 15) * 4;
    #pragma unroll
    for (int i = 0; i < 4; ++i) {
        float4 v = *(const float4*)&src[(size_t)(c0 + i * 16 + cl) * NPTS + p0 + pl4];
        tile[i * 16 + cl][pl4] = v.x; tile[i * 16 + cl][pl4 + 1] = v.y;
        tile[i * 16 + cl][pl4 + 2] = v.z; tile[i * 16 + cl][pl4 + 3] = v.w;
    }
    __syncthreads();
    int pl = t >> 2, cs = t & 3;
    float iv = inv[p0 + pl];
    alignas(16) unsigned short hbuf[16], lbuf[16];
    #pragma unroll
    for (int j = 0; j < 16; ++j) {
        float v = tile[cs * 16 + j][pl] * iv;
        unsigned short h = f2bf(v);
        hbuf[j] = h;
        lbuf[j] = f2bf(v - bf2f(h));
    }
    size_t ob = (size_t)(p0 + pl) * 256 + c0 + cs * 16;
    *(uint4*)&hiT[ob] = *(const uint4*)&hbuf[0];
    *(uint4*)&hiT[ob + 8] = *(const uint4*)&hbuf[8];
    *(uint4*)&loT[ob] = *(const uint4*)&lbuf[0];
    *(uint4*)&loT[ob + 8] = *(const uint4*)&lbuf[8];
}

// sim GEMM 128x128/block, split-bf16 3-term MFMA; hi-streams via gload_lds dbuf
// (32KB LDS -> 3-4 blocks/CU), lo-streams read per-fragment direct from global
// (L2-resident, issued early to hide under hh-MFMAs). Fused in-register top-2s.
__global__ __launch_bounds__(256) void sim_fused_k(const unsigned short* __restrict__ AhT, const unsigned short* __restrict__ AlT,
                                                   const unsigned short* __restrict__ BhT, const unsigned short* __restrict__ BlT,
                                                   float4* __restrict__ prowP, float4* __restrict__ pcolP) {
    __shared__ __align__(16) unsigned short lds[16384];   // 32KB: dbuf x (Ah|Bh) x 128x32

    int bx = blockIdx.x;
    int rb = bx % RB;
    int cb = bx / RB;
    int p0 = rb * 128, q0 = cb * 128;
    int t = threadIdx.x;
    int lane = t & 63, w = t >> 6;
    int wr = w >> 1, wc = w & 1;
    int l15 = lane & 15, kslot = lane >> 4;

    int srow = w * 16 + (lane >> 2);
    int ssw = (srow >> 1) & 3;
    int sgel = ((lane & 3) ^ ssw) * 8;
    size_t gA0 = (size_t)(p0 + srow) * 256 + sgel;
    size_t gA1 = gA0 + (size_t)64 * 256;
    size_t gB0 = (size_t)(q0 + srow) * 256 + sgel;
    size_t gB1 = gB0 + (size_t)64 * 256;
    int lb0 = w * 512;
    int lb1 = 2048 + w * 512;

#define STAGE(b, kc) { size_t ko = (size_t)(kc) * 32; int bb = (b) * 8192; \
        gload16(AhT + gA0 + ko, &lds[bb         + lb0]); \
        gload16(AhT + gA1 + ko, &lds[bb         + lb1]); \
        gload16(BhT + gB0 + ko, &lds[bb + 4096  + lb0]); \
        gload16(BhT + gB1 + ko, &lds[bb + 4096  + lb1]); }

    STAGE(0, 0);

    // per-fragment global addresses for lo-streams (canonical layout, no swizzle)
    size_t aLo[4], bLo[4];
    #pragma unroll
    for (int f = 0; f < 4; ++f) {
        aLo[f] = (size_t)(p0 + wr * 64 + f * 16 + l15) * 256 + kslot * 8;
        bLo[f] = (size_t)(q0 + wc * 64 + f * 16 + l15) * 256 + kslot * 8;
    }

    f32x4 acc[4][4];
    #pragma unroll
    for (int i = 0; i < 4; ++i)
        #pragma unroll
        for (int j2 = 0; j2 < 4; ++j2) acc[i][j2] = (f32x4){0.f, 0.f, 0.f, 0.f};

    __syncthreads();

    for (int kc = 0; kc < 8; ++kc) {
        if (kc < 7) STAGE((kc + 1) & 1, kc + 1);
        size_t ko = (size_t)kc * 32;
        int bb = (kc & 1) * 8192;
        short8 ah[4], bh[4], bl[4], al[4];
        // issue lo B loads early (L2 latency hides under ds_read + hh MFMAs)
        #pragma unroll
        for (int f = 0; f < 4; ++f) bl[f] = *(const short8*)&BlT[bLo[f] + ko];
        #pragma unroll
        for (int f = 0; f < 4; ++f) {
            int R = wr * 64 + f * 16 + l15;
            ah[f] = *(const short8*)&lds[bb + R * 32 + ((kslot ^ ((R >> 1) & 3)) << 3)];
        }
        #pragma unroll
        for (int f = 0; f < 4; ++f) {
            int R = wc * 64 + f * 16 + l15;
            bh[f] = *(const short8*)&lds[bb + 4096 + R * 32 + ((kslot ^ ((R >> 1) & 3)) << 3)];
        }
        #pragma unroll
        for (int i = 0; i < 4; ++i)
            #pragma unroll
            for (int j2 = 0; j2 < 4; ++j2)
                acc[i][j2] = __builtin_amdgcn_mfma_f32_16x16x32_bf16(ah[i], bh[j2], acc[i][j2], 0, 0, 0);
        // issue lo A loads; consume bl meanwhile
        #pragma unroll
        for (int f = 0; f < 4; ++f) al[f] = *(const short8*)&AlT[aLo[f] + ko];
        #pragma unroll
        for (int i = 0; i < 4; ++i)
            #pragma unroll
            for (int j2 = 0; j2 < 4; ++j2)
                acc[i][j2] = __builtin_amdgcn_mfma_f32_16x16x32_bf16(ah[i], bl[j2], acc[i][j2], 0, 0, 0);
        #pragma unroll
        for (int i = 0; i < 4; ++i)
            #pragma unroll
            for (int j2 = 0; j2 < 4; ++j2)
                acc[i][j2] = __builtin_amdgcn_mfma_f32_16x16x32_bf16(al[i], bh[j2], acc[i][j2], 0, 0, 0);
        if (kc < 7) __syncthreads();
    }
#undef STAGE

    // acc[i][j2][r] = sim[p0 + wr*64 + i*16 + kslot*4 + r][q0 + wc*64 + j2*16 + l15]

    // ---- fused col-top2 (over this block's 128 rows): lane-local 16 + shfl over kslot ----
    int rbbase = p0 + wr * 64 + kslot * 4;
    #pragma unroll
    for (int j2 = 0; j2 < 4; ++j2) {
        float pm[8], ps[8]; int pi[8];
        #pragma unroll
        for (int h = 0; h < 8; ++h) {
            int ia = h >> 1, ra = (h & 1) * 2;
            float a = acc[ia][j2][ra], b = acc[ia][j2][ra + 1];
            int idxa = rbbase + ia * 16 + ra;
            pm[h] = fmaxf(a, b); ps[h] = fminf(a, b);
            pi[h] = (b > a) ? idxa + 1 : idxa;
        }
        #pragma unroll
        for (int st = 1; st < 8; st <<= 1)
            #pragma unroll
            for (int h = 0; h < 8; h += 2 * st)
                tmerge(pm[h], ps[h], pi[h], pm[h + st], ps[h + st], pi[h + st]);
        float m = pm[0], s = ps[0]; int ii = pi[0];
        #pragma unroll
        for (int d = 16; d < 64; d <<= 1) {
            float om = __shfl_xor(m, d), os = __shfl_xor(s, d);
            int oi = __shfl_xor(ii, d);
            tmerge(m, s, ii, om, os, oi);
        }
        if (kslot == 0)
            pcolP[(size_t)(wr * RB + rb) * NPTS + q0 + wc * 64 + j2 * 16 + l15] =
                make_float4(m, s, __int_as_float(ii), 0.f);
    }

    // ---- fused row-top2 (over this wave's 64 cols): j2 tree + shfl over l15 ----
    int cbase = q0 + wc * 64 + l15;
    #pragma unroll
    for (int i = 0; i < 4; ++i) {
        float rm_[4], rs_[4]; int ri_[4];
        #pragma unroll
        for (int r = 0; r < 4; ++r) {
            float a = acc[i][0][r], b = acc[i][1][r];
            float m0 = fmaxf(a, b), s0 = fminf(a, b);
            int i0 = (b > a) ? cbase + 16 : cbase;
            float c2 = acc[i][2][r], d2 = acc[i][3][r];
            float m1 = fmaxf(c2, d2), s1 = fminf(c2, d2);
            int i1 = (d2 > c2) ? cbase + 48 : cbase + 32;
            tmerge(m0, s0, i0, m1, s1, i1);
            rm_[r] = m0; rs_[r] = s0; ri_[r] = i0;
        }
        #pragma unroll
        for (int d = 1; d < 16; d <<= 1)
            #pragma unroll
            for (int r = 0; r < 4; ++r) {
                float om = __shfl_xor(rm_[r], d), os = __shfl_xor(rs_[r], d);
                int oi = __shfl_xor(ri_[r], d);
                tmerge(rm_[r], rs_[r], ri_[r], om, os, oi);
            }
        if (l15 == 0) {
            size_t pbase = (size_t)(wc * RB + cb) * NPTS + p0 + wr * 64 + i * 16 + kslot * 4;
            #pragma unroll
            for (int r = 0; r < 4; ++r)
                prowP[pbase + r] = make_float4(rm_[r], rs_[r], __int_as_float(ri_[r]), 0.f);
        }
    }
}

__global__ void merge_rows_k(const float4* __restrict__ prowP, int* __restrict__ nn12,
                             float* __restrict__ msim, float* __restrict__ r12) {
    int p = blockIdx.x * blockDim.x + threadIdx.x;
    if (p >= NPTS) return;
    float m = -3.0e38f, s = -3.0e38f; int ii = 0;
    #pragma unroll 8
    for (int k = 0; k < 2 * RB; ++k) {
        float4 sv = prowP[(size_t)k * NPTS + p];
        tmerge(m, s, ii, sv.x, sv.y, __float_as_int(sv.z));
    }
    nn12[p] = ii; msim[p] = m;
    r12[p] = (2.0f - 2.0f * m) / ((2.0f - 2.0f * s) + 1e-8f);
}

__global__ void merge_cols_k(const float4* __restrict__ pcolP, int* __restrict__ nn21, float* __restrict__ r21) {
    int q = blockIdx.x * blockDim.x + threadIdx.x;
    if (q >= NPTS) return;
    float m = -3.0e38f, s = -3.0e38f; int ii = 0;
    #pragma unroll 8
    for (int k = 0; k < 2 * RB; ++k) {
        float4 sv = pcolP[(size_t)k * NPTS + q];
        tmerge(m, s, ii, sv.x, sv.y, __float_as_int(sv.z));
    }
    nn21[q] = ii;
    r21[q] = (2.0f - 2.0f * m) / ((2.0f - 2.0f * s) + 1e-8f);
}

__global__ void valid_k(const int* __restrict__ nn12, const float* __restrict__ r12,
                        const int* __restrict__ nn21, const float* __restrict__ r21,
                        int* __restrict__ validv) {
    int p = blockIdx.x * blockDim.x + threadIdx.x;
    if (p >= NPTS) return;
    int nn = nn12[p];
    bool mnn = (nn21[nn] == p) && (r12[p] <= 0.95f) && (r21[nn] <= 0.95f);
    int xA = p % WW, yA = p / WW, xB = nn % WW, yB = nn / WW;
    bool disc = (xA == 0) | (xA == WW - 1) | (yA == 0) | (yA == WW - 1) |
                (xB == 0) | (xB == WW - 1) | (yB == 0) | (yB == WW - 1);
    validv[p] = (mnn && !disc) ? 1 : 0;
}

// shared refine math body
__device__ __forceinline__ bool refine_core(int c, const float a[4], const float b[4],
                                            float sm[4], int mAB[4], bool rm[4]) {
    float vals[24];
    #pragma unroll
    for (int i = 0; i < 4; ++i) vals[i] = a[i] * a[i];
    #pragma unroll
    for (int j = 0; j < 4; ++j) vals[4 + j] = b[j] * b[j];
    #pragma unroll
    for (int i = 0; i < 4; ++i)
        #pragma unroll
        for (int j = 0; j < 4; ++j) vals[8 + i * 4 + j] = a[i] * b[j];
    #pragma unroll
    for (int v = 0; v < 24; ++v) {
        float x = vals[v];
        #pragma unroll
        for (int m = 1; m < 64; m <<= 1) x += __shfl_xor(x, m);
        vals[v] = x;
    }
    __shared__ float part[24][4];
    __shared__ float fin[24];
    int wave = c >> 6, lane = c & 63;
    if (lane == 0) {
        #pragma unroll
        for (int v = 0; v < 24; ++v) part[v][wave] = vals[v];
    }
    __syncthreads();
    if (c < 24) fin[c] = part[c][0] + part[c][1] + part[c][2] + part[c][3];
    __syncthreads();
    if (c != 0) return false;

    float rsA[4], rsB[4], sc[4][4];
    #pragma unroll
    for (int i = 0; i < 4; ++i) rsA[i] = 1.0f / sqrtf(fin[i]);
    #pragma unroll
    for (int j = 0; j < 4; ++j) rsB[j] = 1.0f / sqrtf(fin[4 + j]);
    #pragma unroll
    for (int i = 0; i < 4; ++i)
        #pragma unroll
        for (int j = 0; j < 4; ++j) sc[i][j] = fin[8 + i * 4 + j] * rsA[i] * rsB[j];

    float ratA[4], scoreA[4];
    #pragma unroll
    for (int i = 0; i < 4; ++i) {
        float v0 = -3.0e38f, v1 = -3.0e38f; int i0 = 0, i1 = 0;
        #pragma unroll
        for (int j = 0; j < 4; ++j) feed(sc[i][j], j, v0, i0, v1, i1);
        float d0 = 2.0f - 2.0f * v0, d1 = 2.0f - 2.0f * v1;
        ratA[i] = d0 / (d1 + 1e-8f);
        scoreA[i] = d0; mAB[i] = i0;
    }
    float ratB[4]; int mBA[4];
    #pragma unroll
    for (int j = 0; j < 4; ++j) {
        float v0 = -3.0e38f, v1 = -3.0e38f; int i0 = 0, i1 = 0;
        #pragma unroll
        for (int i = 0; i < 4; ++i) feed(sc[i][j], i, v0, i0, v1, i1);
        float d0 = 2.0f - 2.0f * v0, d1 = 2.0f - 2.0f * v1;
        ratB[j] = d0 / (d1 + 1e-8f);
        mBA[j] = i0;
    }
    #pragma unroll
    for (int i = 0; i < 4; ++i) {
        bool cyc = (mBA[mAB[i]] == i);
        rm[i] = (fmaxf(ratA[i], ratB[i]) < 0.9f) && cyc;
    }
    #pragma unroll
    for (int i = 0; i < 4; ++i) sm[i] = rm[i] ? scoreA[i] : 5.0f;
    {
        float v0 = -3.0e38f, v1 = -3.0e38f; int i0 = 0, i1 = 0;
        #pragma unroll
        for (int i = 0; i < 4; ++i) feed(sm[i], i, v0, i0, v1, i1);
        rm[i0] = false; rm[i1] = false;
    }
    return true;
}

// canonical invalid-point result: pA = pB = (2,2). Stored: sm[0..3], rxB[4..7], ryB[8..11]
__global__ __launch_bounds__(256) void canon_refine_k(const float* __restrict__ actA, const float* __restrict__ actB,
                                                      float* __restrict__ canon) {
    int c = threadIdx.x;
    const int nxv[4] = {0, 0, 1, 1};
    const int nyv[4] = {0, 1, 0, 1};
    float a[4], b[4];
    #pragma unroll
    for (int i = 0; i < 4; ++i) {
        a[i] = actA[(size_t)c * MACT + (2 + nyv[i]) * W2 + 2 + nxv[i]];
        b[i] = actB[(size_t)c * MACT + (2 + nyv[i]) * W2 + 2 + nxv[i]];
    }
    float sm[4]; int mAB[4]; bool rm[4];
    if (refine_core(c, a, b, sm, mAB, rm)) {
        #pragma unroll
        for (int i = 0; i < 4; ++i) {
            canon[i] = sm[i];
            canon[4 + i] = (float)(2 + nxv[mAB[i]]);
            canon[8 + i] = (float)(2 + nyv[mAB[i]]);
        }
    }
}

// one block per point; invalid points (the common case) copy the canonical result.
__global__ __launch_bounds__(256) void refine_k(const float* __restrict__ actA, const float* __restrict__ actB,
                                                const int* __restrict__ nn12, const float* __restrict__ msim,
                                                const int* __restrict__ validv, const float* __restrict__ canon,
                                                float* __restrict__ out) {
    int n = blockIdx.x;
    int c = threadIdx.x;
    int val = validv[n];
    const int nxv[4] = {0, 0, 1, 1};
    const int nyv[4] = {0, 1, 0, 1};

    if (!val) {
        if (c == 0) {
            out[n * 5 + 0] = msim[n];
            #pragma unroll
            for (int i = 0; i < 4; ++i) out[n * 5 + 1 + i] = canon[i];
            size_t b2 = (size_t)NPTS * 5;
            #pragma unroll
            for (int i = 0; i < 4; ++i) out[b2 + (size_t)n * 4 + i] = (float)(2 + nxv[i]);
            #pragma unroll
            for (int i = 0; i < 4; ++i) out[b2 + (size_t)NPTS * 4 + (size_t)n * 4 + i] = (float)(2 + nyv[i]);
            size_t b3 = b2 + (size_t)NPTS * 8;
            #pragma unroll
            for (int i = 0; i < 4; ++i) out[b3 + (size_t)n * 4 + i] = canon[4 + i];
            #pragma unroll
            for (int i = 0; i < 4; ++i) out[b3 + (size_t)NPTS * 4 + (size_t)n * 4 + i] = canon[8 + i];
            size_t b4 = b3 + (size_t)NPTS * 8;
            #pragma unroll
            for (int i = 0; i < 4; ++i) out[b4 + (size_t)n * 4 + i] = 0.0f;
        }
        return;
    }

    int nn = nn12[n];
    int pAx = 2 * (n % WW), pAy = 2 * (n / WW);
    int pBx = 2 * (nn % WW), pBy = 2 * (nn / WW);
    float a[4], b[4];
    #pragma unroll
    for (int i = 0; i < 4; ++i) {
        a[i] = actA[(size_t)c * MACT + (pAy + nyv[i]) * W2 + pAx + nxv[i]];
        b[i] = actB[(size_t)c * MACT + (pBy + nyv[i]) * W2 + pBx + nxv[i]];
    }
    float sm[4]; int mAB[4]; bool rm[4];
    if (refine_core(c, a, b, sm, mAB, rm)) {
        out[n * 5 + 0] = msim[n];
        #pragma unroll
        for (int i = 0; i < 4; ++i) out[n * 5 + 1 + i] = sm[i];
        size_t b2 = (size_t)NPTS * 5;
        #pragma unroll
        for (int i = 0; i < 4; ++i) out[b2 + (size_t)n * 4 + i] = (float)(pAx + nxv[i]);
        #pragma unroll
        for (int i = 0; i < 4; ++i) out[b2 + (size_t)NPTS * 4 + (size_t)n * 4 + i] = (float)(pAy + nyv[i]);
        size_t b3 = b2 + (size_t)NPTS * 8;
        #pragma unroll
        for (int i = 0; i < 4; ++i) out[b3 + (size_t)n * 4 + i] = (float)(pBx + nxv[mAB[i]]);
        #pragma unroll
        for (int i = 0; i < 4; ++i) out[b3 + (size_t)NPTS * 4 + (size_t)n * 4 + i] = (float)(pBy + nyv[mAB[i]]);
        size_t b4 = b3 + (size_t)NPTS * 8;
        #pragma unroll
        for (int i = 0; i < 4; ++i) out[b4 + (size_t)n * 4 + i] = rm[i] ? 1.0f : 0.0f;
    }
}

extern "C" void kernel_launch(void* const* d_in, const int* in_sizes, int n_in,
                              void* d_out, int out_size, void* d_ws, size_t ws_size,
                              hipStream_t stream) {
    const float* mapA = (const float*)d_in[0];
    const float* mapB = (const float*)d_in[1];
    const float* actA = (const float*)d_in[2];
    const float* actB = (const float*)d_in[3];
    float* out = (float*)d_out;

    char* wsb = (char*)d_ws;
    size_t szT = (size_t)NPTS * 256 * sizeof(unsigned short);
    unsigned short* AhT = (unsigned short*)wsb;            wsb += szT;
    unsigned short* AlT = (unsigned short*)wsb;            wsb += szT;
    unsigned short* BhT = (unsigned short*)wsb;            wsb += szT;
    unsigned short* BlT = (unsigned short*)wsb;            wsb += szT;
    float4* prowP = (float4*)wsb;                          wsb += (size_t)2 * RB * NPTS * sizeof(float4);
    float4* pcolP = (float4*)wsb;                          wsb += (size_t)2 * RB * NPTS * sizeof(float4);
    float* invA = (float*)wsb;                             wsb += NPTS * sizeof(float);
    float* invB = (float*)wsb;                             wsb += NPTS * sizeof(float);
    int* nn12 = (int*)wsb;                                 wsb += NPTS * sizeof(int);
    float* msim = (float*)wsb;                             wsb += NPTS * sizeof(float);
    float* r12 = (float*)wsb;                              wsb += NPTS * sizeof(float);
    int* nn21 = (int*)wsb;                                 wsb += NPTS * sizeof(int);
    float* r21 = (float*)wsb;                              wsb += NPTS * sizeof(float);
    int* validv = (int*)wsb;                               wsb += NPTS * sizeof(int);
    float* canon = (float*)wsb;

    norm_inv_k<<<NPTS / 256, 256, 0, stream>>>(mapA, invA);
    norm_inv_k<<<NPTS / 256, 256, 0, stream>>>(mapB, invB);
    dim3 gp(NPTS / 64, CDIM / 64);
    prep_split_k<<<gp, 256, 0, stream>>>(mapA, invA, AhT, AlT);
    prep_split_k<<<gp, 256, 0, stream>>>(mapB, invB, BhT, BlT);

    sim_fused_k<<<RB * RB, 256, 0, stream>>>(AhT, AlT, BhT, BlT, prowP, pcolP);

    merge_rows_k<<<NPTS / 256, 256, 0, stream>>>(prowP, nn12, msim, r12);
    merge_cols_k<<<NPTS / 256, 256, 0, stream>>>(pcolP, nn21, r21);
    valid_k<<<NPTS / 256, 256, 0, stream>>>(nn12, r12, nn21, r21, validv);
    canon_refine_k<<<1, 256, 0, stream>>>(actA, actB, canon);
    refine_k<<<NPTS, 256, 0, stream>>>(actA, actB, nn12, msim, validv, canon, out);
}

// Round 14
// 247.097 us; speedup vs baseline: 1.1836x; 1.1836x over previous
//
#include <hip/hip_runtime.h>
#include <math.h>

#define NPTS 9216          // 96*96
#define CDIM 256
#define WW 96
#define W2 192
#define MACT (192*192)
#define RB 72              // 9216/128 row/col blocks

typedef __attribute__((ext_vector_type(8))) short short8;
typedef __attribute__((ext_vector_type(4))) float f32x4;

// branch-free (max, second, argmax-of-max) tuple ops; ties -> keep current (output-invariant)
__device__ __forceinline__ void tmerge(float& m, float& s, int& i, float om, float os, int oi) {
    float lo = fminf(m, om);
    i = (om > m) ? oi : i;
    m = fmaxf(m, om);
    s = fmaxf(fmaxf(s, os), lo);
}

__device__ __forceinline__ void feed(float v, int i, float& v0, int& i0, float& v1, int& i1) {
    if (v > v0) { v1 = v0; i1 = i0; v0 = v; i0 = i; }
    else if (v > v1) { v1 = v; i1 = i; }
}

__device__ __forceinline__ unsigned short f2bf(float f) {
    unsigned u = __float_as_uint(f);
    unsigned r = (u + 0x7fffu + ((u >> 16) & 1u)) >> 16;
    return (unsigned short)r;
}
__device__ __forceinline__ float bf2f(unsigned short h) {
    return __uint_as_float(((unsigned)h) << 16);
}

__device__ __forceinline__ void gload16(const unsigned short* g, unsigned short* l) {
    __builtin_amdgcn_global_load_lds((const __attribute__((address_space(1))) unsigned int*)g,
                                     (__attribute__((address_space(3))) unsigned int*)l, 16, 0, 0);
}

__global__ void norm_inv_k(const float* __restrict__ src, float* __restrict__ inv) {
    int p = blockIdx.x * blockDim.x + threadIdx.x;
    if (p >= NPTS) return;
    float s = 0.f;
    for (int c = 0; c < CDIM; ++c) { float v = src[(size_t)c * NPTS + p]; s += v * v; }
    inv[p] = 1.0f / sqrtf(s);
}

__global__ __launch_bounds__(256) void prep_split_k(const float* __restrict__ src, const float* __restrict__ inv,
                                                    unsigned short* __restrict__ hiT, unsigned short* __restrict__ loT) {
    __shared__ float tile[64][65];
    int p0 = blockIdx.x * 64;
    int c0 = blockIdx.y * 64;
    int t = threadIdx.x;
    int cl = t >> 4, pl4 = (t & 15) * 4;
    #pragma unroll
    for (int i = 0; i < 4; ++i) {
        float4 v = *(const float4*)&src[(size_t)(c0 + i * 16 + cl) * NPTS + p0 + pl4];
        tile[i * 16 + cl][pl4] = v.x; tile[i * 16 + cl][pl4 + 1] = v.y;
        tile[i * 16 + cl][pl4 + 2] = v.z; tile[i * 16 + cl][pl4 + 3] = v.w;
    }
    __syncthreads();
    int pl = t >> 2, cs = t & 3;
    float iv = inv[p0 + pl];
    alignas(16) unsigned short hbuf[16], lbuf[16];
    #pragma unroll
    for (int j = 0; j < 16; ++j) {
        float v = tile[cs * 16 + j][pl] * iv;
        unsigned short h = f2bf(v);
        hbuf[j] = h;
        lbuf[j] = f2bf(v - bf2f(h));
    }
    size_t ob = (size_t)(p0 + pl) * 256 + c0 + cs * 16;
    *(uint4*)&hiT[ob] = *(const uint4*)&hbuf[0];
    *(uint4*)&hiT[ob + 8] = *(const uint4*)&hbuf[8];
    *(uint4*)&loT[ob] = *(const uint4*)&lbuf[0];
    *(uint4*)&loT[ob + 8] = *(const uint4*)&lbuf[8];
}

// sim GEMM 128x128/block, split-bf16 3-term MFMA; BOTH top-2 reductions fused
// in-register (branch-free tuple + shfl trees). No C materialization.
__global__ __launch_bounds__(256) void sim_fused_k(const unsigned short* __restrict__ AhT, const unsigned short* __restrict__ AlT,
                                                   const unsigned short* __restrict__ BhT, const unsigned short* __restrict__ BlT,
                                                   float4* __restrict__ prowP, float4* __restrict__ pcolP) {
    __shared__ __align__(16) unsigned short lds[32768];   // 64KB dbuf

    int bx = blockIdx.x;
    int rb = bx % RB;
    int cb = bx / RB;
    int p0 = rb * 128, q0 = cb * 128;
    int t = threadIdx.x;
    int lane = t & 63, w = t >> 6;
    int wr = w >> 1, wc = w & 1;
    int l15 = lane & 15, kslot = lane >> 4;

    int srow = w * 16 + (lane >> 2);
    int ssw = (srow >> 1) & 3;
    int sgel = ((lane & 3) ^ ssw) * 8;
    size_t gA0 = (size_t)(p0 + srow) * 256 + sgel;
    size_t gA1 = gA0 + (size_t)64 * 256;
    size_t gB0 = (size_t)(q0 + srow) * 256 + sgel;
    size_t gB1 = gB0 + (size_t)64 * 256;
    int lb0 = w * 512;
    int lb1 = 2048 + w * 512;

#define STAGE(b, kc) { size_t ko = (size_t)(kc) * 32; int bb = (b) * 16384; \
        gload16(AhT + gA0 + ko, &lds[bb          + lb0]); \
        gload16(AhT + gA1 + ko, &lds[bb          + lb1]); \
        gload16(AlT + gA0 + ko, &lds[bb +  4096  + lb0]); \
        gload16(AlT + gA1 + ko, &lds[bb +  4096  + lb1]); \
        gload16(BhT + gB0 + ko, &lds[bb +  8192  + lb0]); \
        gload16(BhT + gB1 + ko, &lds[bb +  8192  + lb1]); \
        gload16(BlT + gB0 + ko, &lds[bb + 12288  + lb0]); \
        gload16(BlT + gB1 + ko, &lds[bb + 12288  + lb1]); }

    STAGE(0, 0);

    f32x4 acc[4][4];
    #pragma unroll
    for (int i = 0; i < 4; ++i)
        #pragma unroll
        for (int j2 = 0; j2 < 4; ++j2) acc[i][j2] = (f32x4){0.f, 0.f, 0.f, 0.f};

    __syncthreads();

    for (int kc = 0; kc < 8; ++kc) {
        if (kc < 7) STAGE((kc + 1) & 1, kc + 1);
        int bb = (kc & 1) * 16384;
        short8 ah[4], bh[4], xx[4];
        #pragma unroll
        for (int f = 0; f < 4; ++f) {
            int R = wr * 64 + f * 16 + l15;
            ah[f] = *(const short8*)&lds[bb + R * 32 + ((kslot ^ ((R >> 1) & 3)) << 3)];
        }
        #pragma unroll
        for (int f = 0; f < 4; ++f) {
            int R = wc * 64 + f * 16 + l15;
            bh[f] = *(const short8*)&lds[bb + 8192 + R * 32 + ((kslot ^ ((R >> 1) & 3)) << 3)];
        }
        #pragma unroll
        for (int i = 0; i < 4; ++i)
            #pragma unroll
            for (int j2 = 0; j2 < 4; ++j2)
                acc[i][j2] = __builtin_amdgcn_mfma_f32_16x16x32_bf16(ah[i], bh[j2], acc[i][j2], 0, 0, 0);
        #pragma unroll
        for (int f = 0; f < 4; ++f) {
            int R = wc * 64 + f * 16 + l15;
            xx[f] = *(const short8*)&lds[bb + 12288 + R * 32 + ((kslot ^ ((R >> 1) & 3)) << 3)];
        }
        #pragma unroll
        for (int i = 0; i < 4; ++i)
            #pragma unroll
            for (int j2 = 0; j2 < 4; ++j2)
                acc[i][j2] = __builtin_amdgcn_mfma_f32_16x16x32_bf16(ah[i], xx[j2], acc[i][j2], 0, 0, 0);
        #pragma unroll
        for (int f = 0; f < 4; ++f) {
            int R = wr * 64 + f * 16 + l15;
            xx[f] = *(const short8*)&lds[bb + 4096 + R * 32 + ((kslot ^ ((R >> 1) & 3)) << 3)];
        }
        #pragma unroll
        for (int i = 0; i < 4; ++i)
            #pragma unroll
            for (int j2 = 0; j2 < 4; ++j2)
                acc[i][j2] = __builtin_amdgcn_mfma_f32_16x16x32_bf16(xx[i], bh[j2], acc[i][j2], 0, 0, 0);
        __syncthreads();
    }
#undef STAGE

    // acc[i][j2][r] = sim[p0 + wr*64 + i*16 + kslot*4 + r][q0 + wc*64 + j2*16 + l15]

    // ---- fused col-top2 (over this block's 128 rows): lane-local 16 + shfl over kslot ----
    int rbbase = p0 + wr * 64 + kslot * 4;
    #pragma unroll
    for (int j2 = 0; j2 < 4; ++j2) {
        float pm[8], ps[8]; int pi[8];
        #pragma unroll
        for (int h = 0; h < 8; ++h) {
            int ia = h >> 1, ra = (h & 1) * 2;
            float a = acc[ia][j2][ra], b = acc[ia][j2][ra + 1];
            int idxa = rbbase + ia * 16 + ra;
            pm[h] = fmaxf(a, b); ps[h] = fminf(a, b);
            pi[h] = (b > a) ? idxa + 1 : idxa;
        }
        #pragma unroll
        for (int st = 1; st < 8; st <<= 1)
            #pragma unroll
            for (int h = 0; h < 8; h += 2 * st)
                tmerge(pm[h], ps[h], pi[h], pm[h + st], ps[h + st], pi[h + st]);
        float m = pm[0], s = ps[0]; int ii = pi[0];
        #pragma unroll
        for (int d = 16; d < 64; d <<= 1) {
            float om = __shfl_xor(m, d), os = __shfl_xor(s, d);
            int oi = __shfl_xor(ii, d);
            tmerge(m, s, ii, om, os, oi);
        }
        if (kslot == 0)
            pcolP[(size_t)(wr * RB + rb) * NPTS + q0 + wc * 64 + j2 * 16 + l15] =
                make_float4(m, s, __int_as_float(ii), 0.f);
    }

    // ---- fused row-top2 (over this wave's 64 cols): j2 tree + shfl over l15 ----
    int cbase = q0 + wc * 64 + l15;
    #pragma unroll
    for (int i = 0; i < 4; ++i) {
        float rm_[4], rs_[4]; int ri_[4];
        #pragma unroll
        for (int r = 0; r < 4; ++r) {
            float a = acc[i][0][r], b = acc[i][1][r];
            float m0 = fmaxf(a, b), s0 = fminf(a, b);
            int i0 = (b > a) ? cbase + 16 : cbase;
            float c2 = acc[i][2][r], d2 = acc[i][3][r];
            float m1 = fmaxf(c2, d2), s1 = fminf(c2, d2);
            int i1 = (d2 > c2) ? cbase + 48 : cbase + 32;
            tmerge(m0, s0, i0, m1, s1, i1);
            rm_[r] = m0; rs_[r] = s0; ri_[r] = i0;
        }
        #pragma unroll
        for (int d = 1; d < 16; d <<= 1)
            #pragma unroll
            for (int r = 0; r < 4; ++r) {
                float om = __shfl_xor(rm_[r], d), os = __shfl_xor(rs_[r], d);
                int oi = __shfl_xor(ri_[r], d);
                tmerge(rm_[r], rs_[r], ri_[r], om, os, oi);
            }
        if (l15 == 0) {
            size_t pbase = (size_t)(wc * RB + cb) * NPTS + p0 + wr * 64 + i * 16 + kslot * 4;
            #pragma unroll
            for (int r = 0; r < 4; ++r)
                prowP[pbase + r] = make_float4(rm_[r], rs_[r], __int_as_float(ri_[r]), 0.f);
        }
    }
}

__global__ void merge_rows_k(const float4* __restrict__ prowP, int* __restrict__ nn12,
                             float* __restrict__ msim, float* __restrict__ r12) {
    int p = blockIdx.x * blockDim.x + threadIdx.x;
    if (p >= NPTS) return;
    float m = -3.0e38f, s = -3.0e38f; int ii = 0;
    #pragma unroll 8
    for (int k = 0; k < 2 * RB; ++k) {
        float4 sv = prowP[(size_t)k * NPTS + p];
        tmerge(m, s, ii, sv.x, sv.y, __float_as_int(sv.z));
    }
    nn12[p] = ii; msim[p] = m;
    r12[p] = (2.0f - 2.0f * m) / ((2.0f - 2.0f * s) + 1e-8f);
}

__global__ void merge_cols_k(const float4* __restrict__ pcolP, int* __restrict__ nn21, float* __restrict__ r21) {
    int q = blockIdx.x * blockDim.x + threadIdx.x;
    if (q >= NPTS) return;
    float m = -3.0e38f, s = -3.0e38f; int ii = 0;
    #pragma unroll 8
    for (int k = 0; k < 2 * RB; ++k) {
        float4 sv = pcolP[(size_t)k * NPTS + q];
        tmerge(m, s, ii, sv.x, sv.y, __float_as_int(sv.z));
    }
    nn21[q] = ii;
    r21[q] = (2.0f - 2.0f * m) / ((2.0f - 2.0f * s) + 1e-8f);
}

__global__ void valid_k(const int* __restrict__ nn12, const float* __restrict__ r12,
                        const int* __restrict__ nn21, const float* __restrict__ r21,
                        int* __restrict__ validv) {
    int p = blockIdx.x * blockDim.x + threadIdx.x;
    if (p >= NPTS) return;
    int nn = nn12[p];
    bool mnn = (nn21[nn] == p) && (r12[p] <= 0.95f) && (r21[nn] <= 0.95f);
    int xA = p % WW, yA = p / WW, xB = nn % WW, yB = nn / WW;
    bool disc = (xA == 0) | (xA == WW - 1) | (yA == 0) | (yA == WW - 1) |
                (xB == 0) | (xB == WW - 1) | (yB == 0) | (yB == WW - 1);
    validv[p] = (mnn && !disc) ? 1 : 0;
}

// shared refine math body
__device__ __forceinline__ bool refine_core(int c, const float a[4], const float b[4],
                                            float sm[4], int mAB[4], bool rm[4]) {
    float vals[24];
    #pragma unroll
    for (int i = 0; i < 4; ++i) vals[i] = a[i] * a[i];
    #pragma unroll
    for (int j = 0; j < 4; ++j) vals[4 + j] = b[j] * b[j];
    #pragma unroll
    for (int i = 0; i < 4; ++i)
        #pragma unroll
        for (int j = 0; j < 4; ++j) vals[8 + i * 4 + j] = a[i] * b[j];
    #pragma unroll
    for (int v = 0; v < 24; ++v) {
        float x = vals[v];
        #pragma unroll
        for (int m = 1; m < 64; m <<= 1) x += __shfl_xor(x, m);
        vals[v] = x;
    }
    __shared__ float part[24][4];
    __shared__ float fin[24];
    int wave = c >> 6, lane = c & 63;
    if (lane == 0) {
        #pragma unroll
        for (int v = 0; v < 24; ++v) part[v][wave] = vals[v];
    }
    __syncthreads();
    if (c < 24) fin[c] = part[c][0] + part[c][1] + part[c][2] + part[c][3];
    __syncthreads();
    if (c != 0) return false;

    float rsA[4], rsB[4], sc[4][4];
    #pragma unroll
    for (int i = 0; i < 4; ++i) rsA[i] = 1.0f / sqrtf(fin[i]);
    #pragma unroll
    for (int j = 0; j < 4; ++j) rsB[j] = 1.0f / sqrtf(fin[4 + j]);
    #pragma unroll
    for (int i = 0; i < 4; ++i)
        #pragma unroll
        for (int j = 0; j < 4; ++j) sc[i][j] = fin[8 + i * 4 + j] * rsA[i] * rsB[j];

    float ratA[4], scoreA[4];
    #pragma unroll
    for (int i = 0; i < 4; ++i) {
        float v0 = -3.0e38f, v1 = -3.0e38f; int i0 = 0, i1 = 0;
        #pragma unroll
        for (int j = 0; j < 4; ++j) feed(sc[i][j], j, v0, i0, v1, i1);
        float d0 = 2.0f - 2.0f * v0, d1 = 2.0f - 2.0f * v1;
        ratA[i] = d0 / (d1 + 1e-8f);
        scoreA[i] = d0; mAB[i] = i0;
    }
    float ratB[4]; int mBA[4];
    #pragma unroll
    for (int j = 0; j < 4; ++j) {
        float v0 = -3.0e38f, v1 = -3.0e38f; int i0 = 0, i1 = 0;
        #pragma unroll
        for (int i = 0; i < 4; ++i) feed(sc[i][j], i, v0, i0, v1, i1);
        float d0 = 2.0f - 2.0f * v0, d1 = 2.0f - 2.0f * v1;
        ratB[j] = d0 / (d1 + 1e-8f);
        mBA[j] = i0;
    }
    #pragma unroll
    for (int i = 0; i < 4; ++i) {
        bool cyc = (mBA[mAB[i]] == i);
        rm[i] = (fmaxf(ratA[i], ratB[i]) < 0.9f) && cyc;
    }
    #pragma unroll
    for (int i = 0; i < 4; ++i) sm[i] = rm[i] ? scoreA[i] : 5.0f;
    {
        float v0 = -3.0e38f, v1 = -3.0e38f; int i0 = 0, i1 = 0;
        #pragma unroll
        for (int i = 0; i < 4; ++i) feed(sm[i], i, v0, i0, v1, i1);
        rm[i0] = false; rm[i1] = false;
    }
    return true;
}

// canonical invalid-point result: pA = pB = (2,2). Stored: sm[0..3], rxB[4..7], ryB[8..11]
__global__ __launch_bounds__(256) void canon_refine_k(const float* __restrict__ actA, const float* __restrict__ actB,
                                                      float* __restrict__ canon) {
    int c = threadIdx.x;
    const int nxv[4] = {0, 0, 1, 1};
    const int nyv[4] = {0, 1, 0, 1};
    float a[4], b[4];
    #pragma unroll
    for (int i = 0; i < 4; ++i) {
        a[i] = actA[(size_t)c * MACT + (2 + nyv[i]) * W2 + 2 + nxv[i]];
        b[i] = actB[(size_t)c * MACT + (2 + nyv[i]) * W2 + 2 + nxv[i]];
    }
    float sm[4]; int mAB[4]; bool rm[4];
    if (refine_core(c, a, b, sm, mAB, rm)) {
        #pragma unroll
        for (int i = 0; i < 4; ++i) {
            canon[i] = sm[i];
            canon[4 + i] = (float)(2 + nxv[mAB[i]]);
            canon[8 + i] = (float)(2 + nyv[mAB[i]]);
        }
    }
}

// one block per point; invalid points (the common case) copy the canonical result.
__global__ __launch_bounds__(256) void refine_k(const float* __restrict__ actA, const float* __restrict__ actB,
                                                const int* __restrict__ nn12, const float* __restrict__ msim,
                                                const int* __restrict__ validv, const float* __restrict__ canon,
                                                float* __restrict__ out) {
    int n = blockIdx.x;
    int c = threadIdx.x;
    int val = validv[n];
    const int nxv[4] = {0, 0, 1, 1};
    const int nyv[4] = {0, 1, 0, 1};

    if (!val) {
        if (c == 0) {
            out[n * 5 + 0] = msim[n];
            #pragma unroll
            for (int i = 0; i < 4; ++i) out[n * 5 + 1 + i] = canon[i];
            size_t b2 = (size_t)NPTS * 5;
            #pragma unroll
            for (int i = 0; i < 4; ++i) out[b2 + (size_t)n * 4 + i] = (float)(2 + nxv[i]);
            #pragma unroll
            for (int i = 0; i < 4; ++i) out[b2 + (size_t)NPTS * 4 + (size_t)n * 4 + i] = (float)(2 + nyv[i]);
            size_t b3 = b2 + (size_t)NPTS * 8;
            #pragma unroll
            for (int i = 0; i < 4; ++i) out[b3 + (size_t)n * 4 + i] = canon[4 + i];
            #pragma unroll
            for (int i = 0; i < 4; ++i) out[b3 + (size_t)NPTS * 4 + (size_t)n * 4 + i] = canon[8 + i];
            size_t b4 = b3 + (size_t)NPTS * 8;
            #pragma unroll
            for (int i = 0; i < 4; ++i) out[b4 + (size_t)n * 4 + i] = 0.0f;
        }
        return;
    }

    int nn = nn12[n];
    int pAx = 2 * (n % WW), pAy = 2 * (n / WW);
    int pBx = 2 * (nn % WW), pBy = 2 * (nn / WW);
    float a[4], b[4];
    #pragma unroll
    for (int i = 0; i < 4; ++i) {
        a[i] = actA[(size_t)c * MACT + (pAy + nyv[i]) * W2 + pAx + nxv[i]];
        b[i] = actB[(size_t)c * MACT + (pBy + nyv[i]) * W2 + pBx + nxv[i]];
    }
    float sm[4]; int mAB[4]; bool rm[4];
    if (refine_core(c, a, b, sm, mAB, rm)) {
        out[n * 5 + 0] = msim[n];
        #pragma unroll
        for (int i = 0; i < 4; ++i) out[n * 5 + 1 + i] = sm[i];
        size_t b2 = (size_t)NPTS * 5;
        #pragma unroll
        for (int i = 0; i < 4; ++i) out[b2 + (size_t)n * 4 + i] = (float)(pAx + nxv[i]);
        #pragma unroll
        for (int i = 0; i < 4; ++i) out[b2 + (size_t)NPTS * 4 + (size_t)n * 4 + i] = (float)(pAy + nyv[i]);
        size_t b3 = b2 + (size_t)NPTS * 8;
        #pragma unroll
        for (int i = 0; i < 4; ++i) out[b3 + (size_t)n * 4 + i] = (float)(pBx + nxv[mAB[i]]);
        #pragma unroll
        for (int i = 0; i < 4; ++i) out[b3 + (size_t)NPTS * 4 + (size_t)n * 4 + i] = (float)(pBy + nyv[mAB[i]]);
        size_t b4 = b3 + (size_t)NPTS * 8;
        #pragma unroll
        for (int i = 0; i < 4; ++i) out[b4 + (size_t)n * 4 + i] = rm[i] ? 1.0f : 0.0f;
    }
}

extern "C" void kernel_launch(void* const* d_in, const int* in_sizes, int n_in,
                              void* d_out, int out_size, void* d_ws, size_t ws_size,
                              hipStream_t stream) {
    const float* mapA = (const float*)d_in[0];
    const float* mapB = (const float*)d_in[1];
    const float* actA = (const float*)d_in[2];
    const float* actB = (const float*)d_in[3];
    float* out = (float*)d_out;

    char* wsb = (char*)d_ws;
    size_t szT = (size_t)NPTS * 256 * sizeof(unsigned short);
    unsigned short* AhT = (unsigned short*)wsb;            wsb += szT;
    unsigned short* AlT = (unsigned short*)wsb;            wsb += szT;
    unsigned short* BhT = (unsigned short*)wsb;            wsb += szT;
    unsigned short* BlT = (unsigned short*)wsb;            wsb += szT;
    float4* prowP = (float4*)wsb;                          wsb += (size_t)2 * RB * NPTS * sizeof(float4);
    float4* pcolP = (float4*)wsb;                          wsb += (size_t)2 * RB * NPTS * sizeof(float4);
    float* invA = (float*)wsb;                             wsb += NPTS * sizeof(float);
    float* invB = (float*)wsb;                             wsb += NPTS * sizeof(float);
    int* nn12 = (int*)wsb;                                 wsb += NPTS * sizeof(int);
    float* msim = (float*)wsb;                             wsb += NPTS * sizeof(float);
    float* r12 = (float*)wsb;                              wsb += NPTS * sizeof(float);
    int* nn21 = (int*)wsb;                                 wsb += NPTS * sizeof(int);
    float* r21 = (float*)wsb;                              wsb += NPTS * sizeof(float);
    int* validv = (int*)wsb;                               wsb += NPTS * sizeof(int);
    float* canon = (float*)wsb;

    norm_inv_k<<<NPTS / 256, 256, 0, stream>>>(mapA, invA);
    norm_inv_k<<<NPTS / 256, 256, 0, stream>>>(mapB, invB);
    dim3 gp(NPTS / 64, CDIM / 64);
    prep_split_k<<<gp, 256, 0, stream>>>(mapA, invA, AhT, AlT);
    prep_split_k<<<gp, 256, 0, stream>>>(mapB, invB, BhT, BlT);

    sim_fused_k<<<RB * RB, 256, 0, stream>>>(AhT, AlT, BhT, BlT, prowP, pcolP);

    merge_rows_k<<<NPTS / 256, 256, 0, stream>>>(prowP, nn12, msim, r12);
    merge_cols_k<<<NPTS / 256, 256, 0, stream>>>(pcolP, nn21, r21);
    valid_k<<<NPTS / 256, 256, 0, stream>>>(nn12, r12, nn21, r21, validv);
    canon_refine_k<<<1, 256, 0, stream>>>(actA, actB, canon);
    refine_k<<<NPTS, 256, 0, stream>>>(actA, actB, nn12, msim, validv, canon, out);
}